// Round 1
// baseline (575.332 us; speedup 1.0000x reference)
//
#include <hip/hip_runtime.h>
#include <math.h>

#define NEG_SLOPE 0.2f

// ---------------- CSR build ----------------

__global__ __launch_bounds__(256) void hist_kernel(const int* __restrict__ ei,
                                                   int* __restrict__ counts, int e) {
  int i = blockIdx.x * 256 + threadIdx.x;
  if (i < e) atomicAdd(&counts[ei[e + i]], 1);
}

// exclusive scan of (counts[i] + 1)  (the +1 is the self-loop); offsets[n] = total
__global__ __launch_bounds__(1024) void scan_kernel(const int* __restrict__ counts,
                                                    int* __restrict__ offsets, int n) {
  __shared__ int sdata[1024];
  __shared__ int running_s;
  int tid = threadIdx.x;
  if (tid == 0) running_s = 0;
  __syncthreads();
  for (int base = 0; base < n; base += 1024) {
    int i = base + tid;
    int v = (i < n) ? counts[i] + 1 : 0;
    sdata[tid] = v;
    __syncthreads();
    for (int off = 1; off < 1024; off <<= 1) {
      int t = (tid >= off) ? sdata[tid - off] : 0;
      __syncthreads();
      sdata[tid] += t;
      __syncthreads();
    }
    int run = running_s;
    if (i < n) offsets[i] = run + sdata[tid] - v;  // exclusive
    __syncthreads();
    if (tid == 0) running_s = run + sdata[1023];
    __syncthreads();
  }
  if (tid == 0) offsets[n] = running_s;
}

__global__ __launch_bounds__(256) void fill_kernel(const int* __restrict__ ei,
                                                   int* __restrict__ cursor,
                                                   int* __restrict__ csr, int n, int e) {
  int i = blockIdx.x * 256 + threadIdx.x;
  if (i < e) {
    int s = ei[i];
    int d = ei[e + i];
    int pos = atomicAdd(&cursor[d], 1);
    csr[pos] = s;
  } else if (i < e + n) {
    int node = i - e;  // self loop
    int pos = atomicAdd(&cursor[node], 1);
    csr[pos] = node;
  }
}

// ---------------- GEMM1: h1[n,256] = x[n,128] @ W1[128,256] ----------------
// 64x64 tile, full K=128 staged in LDS, 4x4 register tile per thread.

__global__ __launch_bounds__(256) void gemm1_kernel(const float* __restrict__ x,
                                                    const float* __restrict__ W1,
                                                    float* __restrict__ h1, int n) {
  __shared__ float xst[128][68];  // transposed [k][row], pad 68 for banks + 16B align
  __shared__ float wsm[128][64];
  int tid = threadIdx.x;
  int row0 = blockIdx.x * 64;
  int col0 = blockIdx.y * 64;
#pragma unroll
  for (int i = 0; i < 8; ++i) {
    int flat = tid + i * 256;  // 0..2047
    int r = flat >> 5, c4 = flat & 31;
    float4 v = make_float4(0.f, 0.f, 0.f, 0.f);
    int gr = row0 + r;
    if (gr < n) v = *(const float4*)(x + (size_t)gr * 128 + c4 * 4);
    xst[c4 * 4 + 0][r] = v.x;
    xst[c4 * 4 + 1][r] = v.y;
    xst[c4 * 4 + 2][r] = v.z;
    xst[c4 * 4 + 3][r] = v.w;
  }
#pragma unroll
  for (int i = 0; i < 8; ++i) {
    int flat = tid + i * 256;
    int k = flat >> 4, c4 = flat & 15;
    *(float4*)&wsm[k][c4 * 4] = *(const float4*)(W1 + (size_t)k * 256 + col0 + c4 * 4);
  }
  __syncthreads();
  int tx = tid & 15, ty = tid >> 4;
  int r0 = ty * 4, c0 = tx * 4;
  float acc[4][4] = {};
  for (int k = 0; k < 128; ++k) {
    float4 xv = *(const float4*)&xst[k][r0];
    float4 wv = *(const float4*)&wsm[k][c0];
    float xa[4] = {xv.x, xv.y, xv.z, xv.w};
    float wa[4] = {wv.x, wv.y, wv.z, wv.w};
#pragma unroll
    for (int i2 = 0; i2 < 4; ++i2)
#pragma unroll
      for (int j = 0; j < 4; ++j) acc[i2][j] += xa[i2] * wa[j];
  }
#pragma unroll
  for (int i2 = 0; i2 < 4; ++i2) {
    int gr = row0 + r0 + i2;
    if (gr < n)
      *(float4*)(h1 + (size_t)gr * 256 + col0 + c0) =
          make_float4(acc[i2][0], acc[i2][1], acc[i2][2], acc[i2][3]);
  }
}

// ---------------- attention coefficients, layer 1 ----------------

__global__ __launch_bounds__(256) void att1_kernel(const float* __restrict__ h1,
                                                   const float* __restrict__ att_src,
                                                   const float* __restrict__ att_dst,
                                                   float* __restrict__ as1,
                                                   float* __restrict__ ad1, int n) {
  int idx = blockIdx.x * 256 + threadIdx.x;  // (node, head)
  if (idx >= n * 8) return;
  int node = idx >> 3, h = idx & 7;
  const float4* hp = (const float4*)(h1 + (size_t)node * 256 + h * 32);
  const float4* ap = (const float4*)(att_src + h * 32);
  const float4* bp = (const float4*)(att_dst + h * 32);
  float s1 = 0.f, s2 = 0.f;
#pragma unroll
  for (int c = 0; c < 8; ++c) {
    float4 v = hp[c], a = ap[c], b = bp[c];
    s1 += v.x * a.x + v.y * a.y + v.z * a.z + v.w * a.w;
    s2 += v.x * b.x + v.y * b.y + v.z * b.z + v.w * b.w;
  }
  as1[idx] = s1;
  ad1[idx] = s2;
}

// ---------------- layer-1 aggregation: one wave per dst node ----------------
// lane covers dims [lane*4, lane*4+4) of the 256-wide row; head = lane/8.
// Online softmax; epilogue adds bias and applies ELU.

__global__ __launch_bounds__(256) void agg1_kernel(const float* __restrict__ h1,
                                                   const float* __restrict__ as1,
                                                   const float* __restrict__ ad1,
                                                   const int* __restrict__ offsets,
                                                   const int* __restrict__ csr,
                                                   const float* __restrict__ bias,
                                                   float* __restrict__ h1o, int n) {
  int gtid = blockIdx.x * 256 + threadIdx.x;
  int node = gtid >> 6;
  int lane = gtid & 63;
  if (node >= n) return;
  int head = lane >> 3;
  float ad = ad1[node * 8 + head];
  int beg = offsets[node], end = offsets[node + 1];
  float m = -INFINITY, l = 0.f;
  float ax = 0.f, ay = 0.f, az = 0.f, aw = 0.f;
  for (int p = beg; p < end; ++p) {
    int s = csr[p];
    float ev = as1[s * 8 + head] + ad;
    ev = ev > 0.f ? ev : NEG_SLOPE * ev;
    float mnew = fmaxf(m, ev);
    float scale = __expf(m - mnew);  // first iter: exp(-inf) = 0
    float pe = __expf(ev - mnew);
    l = l * scale + pe;
    float4 hv = *(const float4*)(h1 + (size_t)s * 256 + lane * 4);
    ax = ax * scale + pe * hv.x;
    ay = ay * scale + pe * hv.y;
    az = az * scale + pe * hv.z;
    aw = aw * scale + pe * hv.w;
    m = mnew;
  }
  float inv = 1.f / (l + 1e-16f);
  float4 b = *(const float4*)(bias + lane * 4);
  float o0 = ax * inv + b.x, o1 = ay * inv + b.y;
  float o2 = az * inv + b.z, o3 = aw * inv + b.w;
  o0 = o0 > 0.f ? o0 : expm1f(o0);
  o1 = o1 > 0.f ? o1 : expm1f(o1);
  o2 = o2 > 0.f ? o2 : expm1f(o2);
  o3 = o3 > 0.f ? o3 : expm1f(o3);
  *(float4*)(h1o + (size_t)node * 256 + lane * 4) = make_float4(o0, o1, o2, o3);
}

// ---------------- GEMM2: h2[n,32] = h1o[n,256] @ W2[256,32] ----------------
// 128x32 tile, BK=64, 4x4 register tile per thread.

__global__ __launch_bounds__(256) void gemm2_kernel(const float* __restrict__ h1o,
                                                    const float* __restrict__ W2,
                                                    float* __restrict__ h2, int n) {
  __shared__ float xst[64][132];
  __shared__ float w2s[64][32];
  int tid = threadIdx.x;
  int row0 = blockIdx.x * 128;
  int r0 = (tid >> 3) * 4, c0 = (tid & 7) * 4;
  float acc[4][4] = {};
  for (int k0 = 0; k0 < 256; k0 += 64) {
#pragma unroll
    for (int i = 0; i < 8; ++i) {
      int flat = tid + i * 256;  // 0..2047
      int r = flat >> 4, c4 = flat & 15;
      float4 v = make_float4(0.f, 0.f, 0.f, 0.f);
      int gr = row0 + r;
      if (gr < n) v = *(const float4*)(h1o + (size_t)gr * 256 + k0 + c4 * 4);
      xst[c4 * 4 + 0][r] = v.x;
      xst[c4 * 4 + 1][r] = v.y;
      xst[c4 * 4 + 2][r] = v.z;
      xst[c4 * 4 + 3][r] = v.w;
    }
#pragma unroll
    for (int i = 0; i < 2; ++i) {
      int flat = tid + i * 256;  // 0..511
      int k = flat >> 3, c4 = flat & 7;
      *(float4*)&w2s[k][c4 * 4] = *(const float4*)(W2 + (size_t)(k0 + k) * 32 + c4 * 4);
    }
    __syncthreads();
    for (int k = 0; k < 64; ++k) {
      float4 xv = *(const float4*)&xst[k][r0];
      float4 wv = *(const float4*)&w2s[k][c0];
      float xa[4] = {xv.x, xv.y, xv.z, xv.w};
      float wa[4] = {wv.x, wv.y, wv.z, wv.w};
#pragma unroll
      for (int i2 = 0; i2 < 4; ++i2)
#pragma unroll
        for (int j = 0; j < 4; ++j) acc[i2][j] += xa[i2] * wa[j];
    }
    __syncthreads();
  }
#pragma unroll
  for (int i2 = 0; i2 < 4; ++i2) {
    int gr = row0 + r0 + i2;
    if (gr < n)
      *(float4*)(h2 + (size_t)gr * 32 + c0) =
          make_float4(acc[i2][0], acc[i2][1], acc[i2][2], acc[i2][3]);
  }
}

// ---------------- attention coefficients, layer 2 (1 head) ----------------

__global__ __launch_bounds__(256) void att2_kernel(const float* __restrict__ h2,
                                                   const float* __restrict__ att_src,
                                                   const float* __restrict__ att_dst,
                                                   float* __restrict__ as2,
                                                   float* __restrict__ ad2, int n) {
  int node = blockIdx.x * 256 + threadIdx.x;
  if (node >= n) return;
  const float4* hp = (const float4*)(h2 + (size_t)node * 32);
  const float4* ap = (const float4*)att_src;
  const float4* bp = (const float4*)att_dst;
  float s1 = 0.f, s2 = 0.f;
#pragma unroll
  for (int c = 0; c < 8; ++c) {
    float4 v = hp[c], a = ap[c], b = bp[c];
    s1 += v.x * a.x + v.y * a.y + v.z * a.z + v.w * a.w;
    s2 += v.x * b.x + v.y * b.y + v.z * b.z + v.w * b.w;
  }
  as2[node] = s1;
  ad2[node] = s2;
}

// ---------------- layer-2 aggregation: 32 lanes (half-wave) per node ----------------

__global__ __launch_bounds__(256) void agg2_kernel(const float* __restrict__ h2,
                                                   const float* __restrict__ as2,
                                                   const float* __restrict__ ad2,
                                                   const int* __restrict__ offsets,
                                                   const int* __restrict__ csr,
                                                   const float* __restrict__ bias,
                                                   float* __restrict__ h2o, int n) {
  int gtid = blockIdx.x * 256 + threadIdx.x;
  int node = gtid >> 5;
  int lane = gtid & 31;
  if (node >= n) return;
  float ad = ad2[node];
  int beg = offsets[node], end = offsets[node + 1];
  float m = -INFINITY, l = 0.f, acc = 0.f;
  for (int p = beg; p < end; ++p) {
    int s = csr[p];
    float ev = as2[s] + ad;
    ev = ev > 0.f ? ev : NEG_SLOPE * ev;
    float mnew = fmaxf(m, ev);
    float scale = __expf(m - mnew);
    float pe = __expf(ev - mnew);
    l = l * scale + pe;
    acc = acc * scale + pe * h2[(size_t)s * 32 + lane];
    m = mnew;
  }
  float o = acc / (l + 1e-16f) + bias[lane];
  h2o[(size_t)node * 32 + lane] = o > 0.f ? o : expm1f(o);
}

// ---------------- final: out[n,16] = h2o[n,32] @ Wout[32,16] + bout ----------------

__global__ __launch_bounds__(256) void final_kernel(const float* __restrict__ h2o,
                                                    const float* __restrict__ Wout,
                                                    const float* __restrict__ bout,
                                                    float* __restrict__ out, int n) {
  int t = blockIdx.x * 256 + threadIdx.x;
  if (t >= n * 16) return;
  int node = t >> 4, f = t & 15;
  const float* hp = h2o + (size_t)node * 32;
  float s = bout[f];
#pragma unroll
  for (int c = 0; c < 32; ++c) s += hp[c] * Wout[c * 16 + f];
  out[t] = s;
}

// ---------------- launch ----------------

extern "C" void kernel_launch(void* const* d_in, const int* in_sizes, int n_in,
                              void* d_out, int out_size, void* d_ws, size_t ws_size,
                              hipStream_t stream) {
  const float* x        = (const float*)d_in[0];
  const int*   ei       = (const int*)d_in[1];
  const float* W1       = (const float*)d_in[2];
  const float* att_src1 = (const float*)d_in[3];
  const float* att_dst1 = (const float*)d_in[4];
  const float* b1       = (const float*)d_in[5];
  const float* W2       = (const float*)d_in[6];
  const float* att_src2 = (const float*)d_in[7];
  const float* att_dst2 = (const float*)d_in[8];
  const float* b2       = (const float*)d_in[9];
  const float* Wout     = (const float*)d_in[10];
  const float* bout     = (const float*)d_in[11];
  float* out = (float*)d_out;

  int n = in_sizes[0] / 128;  // 50000
  int e = in_sizes[1] / 2;    // 800000

  char* w = (char*)d_ws;
  float* h1   = (float*)w; w += (size_t)n * 256 * 4;
  float* h1o  = (float*)w; w += (size_t)n * 256 * 4;
  float* h2   = (float*)w; w += (size_t)n * 32 * 4;
  float* h2o  = (float*)w; w += (size_t)n * 32 * 4;
  float* as1  = (float*)w; w += (size_t)n * 8 * 4;
  float* ad1  = (float*)w; w += (size_t)n * 8 * 4;
  float* as2  = (float*)w; w += (size_t)n * 4;
  float* ad2  = (float*)w; w += (size_t)n * 4;
  int* counts  = (int*)w; w += (size_t)n * 4;
  int* offsets = (int*)w; w += (size_t)(n + 1) * 4;
  int* cursor  = (int*)w; w += (size_t)n * 4;
  int* csr     = (int*)w; w += (size_t)(e + n) * 4;

  // CSR by dst (rebuilt every call; edges are restored each call by harness)
  hipMemsetAsync(counts, 0, (size_t)n * 4, stream);
  hist_kernel<<<(e + 255) / 256, 256, 0, stream>>>(ei, counts, e);
  scan_kernel<<<1, 1024, 0, stream>>>(counts, offsets, n);
  hipMemcpyAsync(cursor, offsets, (size_t)n * 4, hipMemcpyDeviceToDevice, stream);
  fill_kernel<<<(e + n + 255) / 256, 256, 0, stream>>>(ei, cursor, csr, n, e);

  // layer 1
  gemm1_kernel<<<dim3((n + 63) / 64, 4), 256, 0, stream>>>(x, W1, h1, n);
  att1_kernel<<<(n * 8 + 255) / 256, 256, 0, stream>>>(h1, att_src1, att_dst1, as1, ad1, n);
  agg1_kernel<<<(n + 3) / 4, 256, 0, stream>>>(h1, as1, ad1, offsets, csr, b1, h1o, n);

  // layer 2
  gemm2_kernel<<<(n + 127) / 128, 256, 0, stream>>>(h1o, W2, h2, n);
  att2_kernel<<<(n + 255) / 256, 256, 0, stream>>>(h2, att_src2, att_dst2, as2, ad2, n);
  agg2_kernel<<<(n * 32 + 255) / 256, 256, 0, stream>>>(h2, as2, ad2, offsets, csr, b2, h2o, n);

  // output projection
  final_kernel<<<(n * 16 + 255) / 256, 256, 0, stream>>>(h2o, Wout, bout, out, n);
}

// Round 2
// 482.105 us; speedup vs baseline: 1.1934x; 1.1934x over previous
//
#include <hip/hip_runtime.h>
#include <math.h>

#define NEG_SLOPE 0.2f

// ---------------- CSR build ----------------

__global__ __launch_bounds__(256) void hist_kernel(const int* __restrict__ ei,
                                                   int* __restrict__ counts, int e) {
  int i = blockIdx.x * 256 + threadIdx.x;
  if (i < e) atomicAdd(&counts[ei[e + i]], 1);
}

// Two-level scan of v[i] = counts[i] + 1 (self-loop adds 1).
// k1: per-2048-tile exclusive scan into offsets[], tile totals into bsum[].
#define SCAN_TILE 2048
__global__ __launch_bounds__(1024) void scan1_kernel(const int* __restrict__ counts,
                                                     int* __restrict__ offsets,
                                                     int* __restrict__ bsum, int n) {
  __shared__ int sdata[SCAN_TILE];
  int tid = threadIdx.x;
  int base = blockIdx.x * SCAN_TILE;
#pragma unroll
  for (int j = 0; j < 2; ++j) {
    int i = base + tid + j * 1024;
    sdata[tid + j * 1024] = (i < n) ? counts[i] + 1 : 0;
  }
  __syncthreads();
  // Hillis-Steele inclusive scan over 2048 (11 rounds), 2 elems/thread
  for (int off = 1; off < SCAN_TILE; off <<= 1) {
    int t0 = 0, t1 = 0;
    int i0 = tid, i1 = tid + 1024;
    if (i0 >= off) t0 = sdata[i0 - off];
    if (i1 >= off) t1 = sdata[i1 - off];
    __syncthreads();
    sdata[i0] += t0;
    sdata[i1] += t1;
    __syncthreads();
  }
#pragma unroll
  for (int j = 0; j < 2; ++j) {
    int li = tid + j * 1024;
    int i = base + li;
    if (i < n) {
      int incl = sdata[li];
      int v = (li == 0) ? incl : incl - sdata[li - 1];
      (void)v;
      offsets[i] = incl;  // inclusive for now; k3 converts
    }
  }
  if (tid == 0) bsum[blockIdx.x] = sdata[SCAN_TILE - 1];
}

// k2: single-wave exclusive scan of tile sums (nb <= 64)
__global__ __launch_bounds__(64) void scan2_kernel(int* __restrict__ bsum, int nb) {
  int tid = threadIdx.x;
  int v = (tid < nb) ? bsum[tid] : 0;
  // inclusive scan via shuffles over 64 lanes
#pragma unroll
  for (int off = 1; off < 64; off <<= 1) {
    int t = __shfl_up(v, off, 64);
    if (tid >= off) v += t;
  }
  if (tid < nb) bsum[tid] = v;  // inclusive tile-sum scan
}

// k3: convert to exclusive global offsets: offsets_excl[i] = incl[i] - v[i] + pre(tile)
// We instead compute: excl[i] = (incl[i] + tilepre) - v[i]. Simpler: shift.
// offsets_out[i] = tilepre(b) + incl[i] - v[i]. We don't have v; use incl[i-1] (or 0).
__global__ __launch_bounds__(256) void scan3_kernel(const int* __restrict__ counts,
                                                    int* __restrict__ offsets,
                                                    const int* __restrict__ bsum,
                                                    int n, int nb) {
  int i = blockIdx.x * 256 + threadIdx.x;
  if (i > n) return;
  if (i == n) {
    offsets[n] = bsum[nb - 1];  // total (after k2, inclusive scan)
    return;
  }
  int b = i / SCAN_TILE;
  int pre = (b == 0) ? 0 : bsum[b - 1];
  int incl = offsets[i];
  int v = counts[i] + 1;
  offsets[i] = pre + incl - v;  // exclusive
}

__global__ __launch_bounds__(256) void fill_kernel(const int* __restrict__ ei,
                                                   int* __restrict__ cursor,
                                                   int* __restrict__ csr, int n, int e) {
  int i = blockIdx.x * 256 + threadIdx.x;
  if (i < e) {
    int s = ei[i];
    int d = ei[e + i];
    int pos = atomicAdd(&cursor[d], 1);
    csr[pos] = s;
  } else if (i < e + n) {
    int node = i - e;  // self loop
    int pos = atomicAdd(&cursor[node], 1);
    csr[pos] = node;
  }
}

// ---------------- GEMM1: h1[n,256] = x[n,128] @ W1[128,256] ----------------

__global__ __launch_bounds__(256) void gemm1_kernel(const float* __restrict__ x,
                                                    const float* __restrict__ W1,
                                                    float* __restrict__ h1, int n) {
  __shared__ float xst[128][68];
  __shared__ float wsm[128][64];
  int tid = threadIdx.x;
  int row0 = blockIdx.x * 64;
  int col0 = blockIdx.y * 64;
#pragma unroll
  for (int i = 0; i < 8; ++i) {
    int flat = tid + i * 256;
    int r = flat >> 5, c4 = flat & 31;
    float4 v = make_float4(0.f, 0.f, 0.f, 0.f);
    int gr = row0 + r;
    if (gr < n) v = *(const float4*)(x + (size_t)gr * 128 + c4 * 4);
    xst[c4 * 4 + 0][r] = v.x;
    xst[c4 * 4 + 1][r] = v.y;
    xst[c4 * 4 + 2][r] = v.z;
    xst[c4 * 4 + 3][r] = v.w;
  }
#pragma unroll
  for (int i = 0; i < 8; ++i) {
    int flat = tid + i * 256;
    int k = flat >> 4, c4 = flat & 15;
    *(float4*)&wsm[k][c4 * 4] = *(const float4*)(W1 + (size_t)k * 256 + col0 + c4 * 4);
  }
  __syncthreads();
  int tx = tid & 15, ty = tid >> 4;
  int r0 = ty * 4, c0 = tx * 4;
  float acc[4][4] = {};
  for (int k = 0; k < 128; ++k) {
    float4 xv = *(const float4*)&xst[k][r0];
    float4 wv = *(const float4*)&wsm[k][c0];
    float xa[4] = {xv.x, xv.y, xv.z, xv.w};
    float wa[4] = {wv.x, wv.y, wv.z, wv.w};
#pragma unroll
    for (int i2 = 0; i2 < 4; ++i2)
#pragma unroll
      for (int j = 0; j < 4; ++j) acc[i2][j] += xa[i2] * wa[j];
  }
#pragma unroll
  for (int i2 = 0; i2 < 4; ++i2) {
    int gr = row0 + r0 + i2;
    if (gr < n)
      *(float4*)(h1 + (size_t)gr * 256 + col0 + c0) =
          make_float4(acc[i2][0], acc[i2][1], acc[i2][2], acc[i2][3]);
  }
}

// ---------------- attention coefficients, layer 1 ----------------

__global__ __launch_bounds__(256) void att1_kernel(const float* __restrict__ h1,
                                                   const float* __restrict__ att_src,
                                                   const float* __restrict__ att_dst,
                                                   float* __restrict__ as1,
                                                   float* __restrict__ ad1, int n) {
  int idx = blockIdx.x * 256 + threadIdx.x;
  if (idx >= n * 8) return;
  int node = idx >> 3, h = idx & 7;
  const float4* hp = (const float4*)(h1 + (size_t)node * 256 + h * 32);
  const float4* ap = (const float4*)(att_src + h * 32);
  const float4* bp = (const float4*)(att_dst + h * 32);
  float s1 = 0.f, s2 = 0.f;
#pragma unroll
  for (int c = 0; c < 8; ++c) {
    float4 v = hp[c], a = ap[c], b = bp[c];
    s1 += v.x * a.x + v.y * a.y + v.z * a.z + v.w * a.w;
    s2 += v.x * b.x + v.y * b.y + v.z * b.z + v.w * b.w;
  }
  as1[idx] = s1;
  ad1[idx] = s2;
}

// ---------------- layer-1 aggregation: one wave per dst node ----------------
// TWO-PHASE softmax: pass A finds max (no exp, no gather — loads pipeline),
// pass B accumulates pe*h with an order-free sum (loads pipeline, 1 exp/edge).

__global__ __launch_bounds__(256) void agg1_kernel(const float* __restrict__ h1,
                                                   const float* __restrict__ as1,
                                                   const float* __restrict__ ad1,
                                                   const int* __restrict__ offsets,
                                                   const int* __restrict__ csr,
                                                   const float* __restrict__ bias,
                                                   float* __restrict__ h1o, int n) {
  int gtid = blockIdx.x * 256 + threadIdx.x;
  int node = gtid >> 6;
  int lane = gtid & 63;
  if (node >= n) return;
  int head = lane >> 3;
  float ad = ad1[node * 8 + head];
  int beg = offsets[node], end = offsets[node + 1];
  // pass A: max
  float m = -INFINITY;
#pragma unroll 4
  for (int p = beg; p < end; ++p) {
    int s = csr[p];
    float ev = as1[s * 8 + head] + ad;
    ev = ev > 0.f ? ev : NEG_SLOPE * ev;
    m = fmaxf(m, ev);
  }
  // pass B: weighted sum (order-free, pipelines)
  float l = 0.f;
  float ax = 0.f, ay = 0.f, az = 0.f, aw = 0.f;
#pragma unroll 4
  for (int p = beg; p < end; ++p) {
    int s = csr[p];
    float ev = as1[s * 8 + head] + ad;
    ev = ev > 0.f ? ev : NEG_SLOPE * ev;
    float pe = __expf(ev - m);
    l += pe;
    float4 hv = *(const float4*)(h1 + (size_t)s * 256 + lane * 4);
    ax += pe * hv.x;
    ay += pe * hv.y;
    az += pe * hv.z;
    aw += pe * hv.w;
  }
  float inv = 1.f / (l + 1e-16f);
  float4 b = *(const float4*)(bias + lane * 4);
  float o0 = ax * inv + b.x, o1 = ay * inv + b.y;
  float o2 = az * inv + b.z, o3 = aw * inv + b.w;
  o0 = o0 > 0.f ? o0 : expm1f(o0);
  o1 = o1 > 0.f ? o1 : expm1f(o1);
  o2 = o2 > 0.f ? o2 : expm1f(o2);
  o3 = o3 > 0.f ? o3 : expm1f(o3);
  *(float4*)(h1o + (size_t)node * 256 + lane * 4) = make_float4(o0, o1, o2, o3);
}

// ---------------- GEMM2: h2[n,32] = h1o[n,256] @ W2[256,32] ----------------

__global__ __launch_bounds__(256) void gemm2_kernel(const float* __restrict__ h1o,
                                                    const float* __restrict__ W2,
                                                    float* __restrict__ h2, int n) {
  __shared__ float xst[64][132];
  __shared__ float w2s[64][32];
  int tid = threadIdx.x;
  int row0 = blockIdx.x * 128;
  int r0 = (tid >> 3) * 4, c0 = (tid & 7) * 4;
  float acc[4][4] = {};
  for (int k0 = 0; k0 < 256; k0 += 64) {
#pragma unroll
    for (int i = 0; i < 8; ++i) {
      int flat = tid + i * 256;
      int r = flat >> 4, c4 = flat & 15;
      float4 v = make_float4(0.f, 0.f, 0.f, 0.f);
      int gr = row0 + r;
      if (gr < n) v = *(const float4*)(h1o + (size_t)gr * 256 + k0 + c4 * 4);
      xst[c4 * 4 + 0][r] = v.x;
      xst[c4 * 4 + 1][r] = v.y;
      xst[c4 * 4 + 2][r] = v.z;
      xst[c4 * 4 + 3][r] = v.w;
    }
#pragma unroll
    for (int i = 0; i < 2; ++i) {
      int flat = tid + i * 256;
      int k = flat >> 3, c4 = flat & 7;
      *(float4*)&w2s[k][c4 * 4] = *(const float4*)(W2 + (size_t)(k0 + k) * 32 + c4 * 4);
    }
    __syncthreads();
    for (int k = 0; k < 64; ++k) {
      float4 xv = *(const float4*)&xst[k][r0];
      float4 wv = *(const float4*)&w2s[k][c0];
      float xa[4] = {xv.x, xv.y, xv.z, xv.w};
      float wa[4] = {wv.x, wv.y, wv.z, wv.w};
#pragma unroll
      for (int i2 = 0; i2 < 4; ++i2)
#pragma unroll
        for (int j = 0; j < 4; ++j) acc[i2][j] += xa[i2] * wa[j];
    }
    __syncthreads();
  }
#pragma unroll
  for (int i2 = 0; i2 < 4; ++i2) {
    int gr = row0 + r0 + i2;
    if (gr < n)
      *(float4*)(h2 + (size_t)gr * 32 + c0) =
          make_float4(acc[i2][0], acc[i2][1], acc[i2][2], acc[i2][3]);
  }
}

// ---------------- attention coefficients, layer 2 (1 head) ----------------

__global__ __launch_bounds__(256) void att2_kernel(const float* __restrict__ h2,
                                                   const float* __restrict__ att_src,
                                                   const float* __restrict__ att_dst,
                                                   float* __restrict__ as2,
                                                   float* __restrict__ ad2, int n) {
  int node = blockIdx.x * 256 + threadIdx.x;
  if (node >= n) return;
  const float4* hp = (const float4*)(h2 + (size_t)node * 32);
  const float4* ap = (const float4*)att_src;
  const float4* bp = (const float4*)att_dst;
  float s1 = 0.f, s2 = 0.f;
#pragma unroll
  for (int c = 0; c < 8; ++c) {
    float4 v = hp[c], a = ap[c], b = bp[c];
    s1 += v.x * a.x + v.y * a.y + v.z * a.z + v.w * a.w;
    s2 += v.x * b.x + v.y * b.y + v.z * b.z + v.w * b.w;
  }
  as2[node] = s1;
  ad2[node] = s2;
}

// ---------------- layer-2 aggregation: 32 lanes per node, two-phase ----------------

__global__ __launch_bounds__(256) void agg2_kernel(const float* __restrict__ h2,
                                                   const float* __restrict__ as2,
                                                   const float* __restrict__ ad2,
                                                   const int* __restrict__ offsets,
                                                   const int* __restrict__ csr,
                                                   const float* __restrict__ bias,
                                                   float* __restrict__ h2o, int n) {
  int gtid = blockIdx.x * 256 + threadIdx.x;
  int node = gtid >> 5;
  int lane = gtid & 31;
  if (node >= n) return;
  float ad = ad2[node];
  int beg = offsets[node], end = offsets[node + 1];
  float m = -INFINITY;
#pragma unroll 4
  for (int p = beg; p < end; ++p) {
    int s = csr[p];
    float ev = as2[s] + ad;
    ev = ev > 0.f ? ev : NEG_SLOPE * ev;
    m = fmaxf(m, ev);
  }
  float l = 0.f, acc = 0.f;
#pragma unroll 4
  for (int p = beg; p < end; ++p) {
    int s = csr[p];
    float ev = as2[s] + ad;
    ev = ev > 0.f ? ev : NEG_SLOPE * ev;
    float pe = __expf(ev - m);
    l += pe;
    acc += pe * h2[(size_t)s * 32 + lane];
  }
  float o = acc / (l + 1e-16f) + bias[lane];
  h2o[(size_t)node * 32 + lane] = o > 0.f ? o : expm1f(o);
}

// ---------------- final: out[n,16] = h2o[n,32] @ Wout[32,16] + bout ----------------

__global__ __launch_bounds__(256) void final_kernel(const float* __restrict__ h2o,
                                                    const float* __restrict__ Wout,
                                                    const float* __restrict__ bout,
                                                    float* __restrict__ out, int n) {
  int t = blockIdx.x * 256 + threadIdx.x;
  if (t >= n * 16) return;
  int node = t >> 4, f = t & 15;
  const float* hp = h2o + (size_t)node * 32;
  float s = bout[f];
#pragma unroll
  for (int c = 0; c < 32; ++c) s += hp[c] * Wout[c * 16 + f];
  out[t] = s;
}

// ---------------- launch ----------------

extern "C" void kernel_launch(void* const* d_in, const int* in_sizes, int n_in,
                              void* d_out, int out_size, void* d_ws, size_t ws_size,
                              hipStream_t stream) {
  const float* x        = (const float*)d_in[0];
  const int*   ei       = (const int*)d_in[1];
  const float* W1       = (const float*)d_in[2];
  const float* att_src1 = (const float*)d_in[3];
  const float* att_dst1 = (const float*)d_in[4];
  const float* b1       = (const float*)d_in[5];
  const float* W2       = (const float*)d_in[6];
  const float* att_src2 = (const float*)d_in[7];
  const float* att_dst2 = (const float*)d_in[8];
  const float* b2       = (const float*)d_in[9];
  const float* Wout     = (const float*)d_in[10];
  const float* bout     = (const float*)d_in[11];
  float* out = (float*)d_out;

  int n = in_sizes[0] / 128;  // 50000
  int e = in_sizes[1] / 2;    // 800000

  char* w = (char*)d_ws;
  float* h1   = (float*)w; w += (size_t)n * 256 * 4;
  float* h1o  = (float*)w; w += (size_t)n * 256 * 4;
  float* h2   = (float*)w; w += (size_t)n * 32 * 4;
  float* h2o  = (float*)w; w += (size_t)n * 32 * 4;
  float* as1  = (float*)w; w += (size_t)n * 8 * 4;
  float* ad1  = (float*)w; w += (size_t)n * 8 * 4;
  float* as2  = (float*)w; w += (size_t)n * 4;
  float* ad2  = (float*)w; w += (size_t)n * 4;
  int* counts  = (int*)w; w += (size_t)n * 4;
  int* offsets = (int*)w; w += (size_t)(n + 1) * 4;
  int* cursor  = (int*)w; w += (size_t)n * 4;
  int* csr     = (int*)w; w += (size_t)(e + n) * 4;
  int* bsum    = (int*)w; w += (size_t)256 * 4;

  int nb = (n + SCAN_TILE - 1) / SCAN_TILE;  // 25 tiles

  // CSR by dst
  hipMemsetAsync(counts, 0, (size_t)n * 4, stream);
  hist_kernel<<<(e + 255) / 256, 256, 0, stream>>>(ei, counts, e);
  scan1_kernel<<<nb, 1024, 0, stream>>>(counts, offsets, bsum, n);
  scan2_kernel<<<1, 64, 0, stream>>>(bsum, nb);
  scan3_kernel<<<(n + 256) / 256, 256, 0, stream>>>(counts, offsets, bsum, n, nb);
  hipMemcpyAsync(cursor, offsets, (size_t)n * 4, hipMemcpyDeviceToDevice, stream);
  fill_kernel<<<(e + n + 255) / 256, 256, 0, stream>>>(ei, cursor, csr, n, e);

  // layer 1
  gemm1_kernel<<<dim3((n + 63) / 64, 4), 256, 0, stream>>>(x, W1, h1, n);
  att1_kernel<<<(n * 8 + 255) / 256, 256, 0, stream>>>(h1, att_src1, att_dst1, as1, ad1, n);
  agg1_kernel<<<(n + 3) / 4, 256, 0, stream>>>(h1, as1, ad1, offsets, csr, b1, h1o, n);

  // layer 2
  gemm2_kernel<<<(n + 127) / 128, 256, 0, stream>>>(h1o, W2, h2, n);
  att2_kernel<<<(n + 255) / 256, 256, 0, stream>>>(h2, att_src2, att_dst2, as2, ad2, n);
  agg2_kernel<<<(n * 32 + 255) / 256, 256, 0, stream>>>(h2, as2, ad2, offsets, csr, b2, h2o, n);

  // output projection
  final_kernel<<<(n * 16 + 255) / 256, 256, 0, stream>>>(h2o, Wout, bout, out, n);
}

// Round 3
// 420.599 us; speedup vs baseline: 1.3679x; 1.1462x over previous
//
#include <hip/hip_runtime.h>
#include <math.h>

#define NEG_SLOPE 0.2f

__device__ __forceinline__ float bf2f(unsigned short u) {
  union { unsigned int i; float f; } c;
  c.i = ((unsigned int)u) << 16;
  return c.f;
}
__device__ __forceinline__ unsigned short f2bf(float f) {
  union { float f; unsigned int i; } c;
  c.f = f;
  unsigned int i = c.i;
  return (unsigned short)((i + 0x7FFFu + ((i >> 16) & 1u)) >> 16);
}

// ---------------- CSR build ----------------

__global__ __launch_bounds__(256) void hist_kernel(const int* __restrict__ ei,
                                                   int* __restrict__ counts, int e) {
  int i = blockIdx.x * 256 + threadIdx.x;
  if (i < e) atomicAdd(&counts[ei[e + i]], 1);
}

#define SCAN_TILE 2048
__global__ __launch_bounds__(1024) void scan1_kernel(const int* __restrict__ counts,
                                                     int* __restrict__ offsets,
                                                     int* __restrict__ bsum, int n) {
  __shared__ int sdata[SCAN_TILE];
  int tid = threadIdx.x;
  int base = blockIdx.x * SCAN_TILE;
#pragma unroll
  for (int j = 0; j < 2; ++j) {
    int i = base + tid + j * 1024;
    sdata[tid + j * 1024] = (i < n) ? counts[i] + 1 : 0;
  }
  __syncthreads();
  for (int off = 1; off < SCAN_TILE; off <<= 1) {
    int t0 = 0, t1 = 0;
    int i0 = tid, i1 = tid + 1024;
    if (i0 >= off) t0 = sdata[i0 - off];
    if (i1 >= off) t1 = sdata[i1 - off];
    __syncthreads();
    sdata[i0] += t0;
    sdata[i1] += t1;
    __syncthreads();
  }
#pragma unroll
  for (int j = 0; j < 2; ++j) {
    int li = tid + j * 1024;
    int i = base + li;
    if (i < n) offsets[i] = sdata[li];  // inclusive; scan3 converts
  }
  if (tid == 0) bsum[blockIdx.x] = sdata[SCAN_TILE - 1];
}

__global__ __launch_bounds__(64) void scan2_kernel(int* __restrict__ bsum, int nb) {
  int tid = threadIdx.x;
  int v = (tid < nb) ? bsum[tid] : 0;
#pragma unroll
  for (int off = 1; off < 64; off <<= 1) {
    int t = __shfl_up(v, off, 64);
    if (tid >= off) v += t;
  }
  if (tid < nb) bsum[tid] = v;
}

__global__ __launch_bounds__(256) void scan3_kernel(const int* __restrict__ counts,
                                                    int* __restrict__ offsets,
                                                    const int* __restrict__ bsum,
                                                    int n, int nb) {
  int i = blockIdx.x * 256 + threadIdx.x;
  if (i > n) return;
  if (i == n) {
    offsets[n] = bsum[nb - 1];
    return;
  }
  int b = i / SCAN_TILE;
  int pre = (b == 0) ? 0 : bsum[b - 1];
  int incl = offsets[i];
  int v = counts[i] + 1;
  offsets[i] = pre + incl - v;
}

__global__ __launch_bounds__(256) void fill_kernel(const int* __restrict__ ei,
                                                   int* __restrict__ cursor,
                                                   int* __restrict__ csr, int n, int e) {
  int i = blockIdx.x * 256 + threadIdx.x;
  if (i < e) {
    int s = ei[i];
    int d = ei[e + i];
    int pos = atomicAdd(&cursor[d], 1);
    csr[pos] = s;
  } else if (i < e + n) {
    int node = i - e;
    int pos = atomicAdd(&cursor[node], 1);
    csr[pos] = node;
  }
}

// ---------------- GEMM1: h1b[n,256] = bf16(x[n,128] @ W1[128,256]) ----------------

__global__ __launch_bounds__(256) void gemm1_kernel(const float* __restrict__ x,
                                                    const float* __restrict__ W1,
                                                    unsigned short* __restrict__ h1b, int n) {
  __shared__ float xst[128][68];
  __shared__ float wsm[128][64];
  int tid = threadIdx.x;
  int row0 = blockIdx.x * 64;
  int col0 = blockIdx.y * 64;
#pragma unroll
  for (int i = 0; i < 8; ++i) {
    int flat = tid + i * 256;
    int r = flat >> 5, c4 = flat & 31;
    float4 v = make_float4(0.f, 0.f, 0.f, 0.f);
    int gr = row0 + r;
    if (gr < n) v = *(const float4*)(x + (size_t)gr * 128 + c4 * 4);
    xst[c4 * 4 + 0][r] = v.x;
    xst[c4 * 4 + 1][r] = v.y;
    xst[c4 * 4 + 2][r] = v.z;
    xst[c4 * 4 + 3][r] = v.w;
  }
#pragma unroll
  for (int i = 0; i < 8; ++i) {
    int flat = tid + i * 256;
    int k = flat >> 4, c4 = flat & 15;
    *(float4*)&wsm[k][c4 * 4] = *(const float4*)(W1 + (size_t)k * 256 + col0 + c4 * 4);
  }
  __syncthreads();
  int tx = tid & 15, ty = tid >> 4;
  int r0 = ty * 4, c0 = tx * 4;
  float acc[4][4] = {};
  for (int k = 0; k < 128; ++k) {
    float4 xv = *(const float4*)&xst[k][r0];
    float4 wv = *(const float4*)&wsm[k][c0];
    float xa[4] = {xv.x, xv.y, xv.z, xv.w};
    float wa[4] = {wv.x, wv.y, wv.z, wv.w};
#pragma unroll
    for (int i2 = 0; i2 < 4; ++i2)
#pragma unroll
      for (int j = 0; j < 4; ++j) acc[i2][j] += xa[i2] * wa[j];
  }
#pragma unroll
  for (int i2 = 0; i2 < 4; ++i2) {
    int gr = row0 + r0 + i2;
    if (gr < n) {
      ushort4 o;
      o.x = f2bf(acc[i2][0]);
      o.y = f2bf(acc[i2][1]);
      o.z = f2bf(acc[i2][2]);
      o.w = f2bf(acc[i2][3]);
      *(ushort4*)(h1b + (size_t)gr * 256 + col0 + c0) = o;
    }
  }
}

// ---------------- attention coefficients, layer 1 ----------------

__global__ __launch_bounds__(256) void att1_kernel(const unsigned short* __restrict__ h1b,
                                                   const float* __restrict__ att_src,
                                                   const float* __restrict__ att_dst,
                                                   float* __restrict__ as1,
                                                   float* __restrict__ ad1, int n) {
  int idx = blockIdx.x * 256 + threadIdx.x;
  if (idx >= n * 8) return;
  int node = idx >> 3, h = idx & 7;
  const ushort4* hp = (const ushort4*)(h1b + (size_t)node * 256 + h * 32);
  const float4* ap = (const float4*)(att_src + h * 32);
  const float4* bp = (const float4*)(att_dst + h * 32);
  float s1 = 0.f, s2 = 0.f;
#pragma unroll
  for (int c = 0; c < 8; ++c) {
    ushort4 u = hp[c];
    float4 a = ap[c], b = bp[c];
    float vx = bf2f(u.x), vy = bf2f(u.y), vz = bf2f(u.z), vw = bf2f(u.w);
    s1 += vx * a.x + vy * a.y + vz * a.z + vw * a.w;
    s2 += vx * b.x + vy * b.y + vz * b.z + vw * b.w;
  }
  as1[idx] = s1;
  ad1[idx] = s2;
}

// ---------------- layer-1 aggregation: one wave per dst node ----------------
// Pass A: 8 edge-slots x 8 heads in parallel (coalesced as1 reads), shfl-xor max.
// Pass B: serial edges, csr broadcast from registers, bf16 512B row gathers.

__global__ __launch_bounds__(256) void agg1_kernel(const unsigned short* __restrict__ h1b,
                                                   const float* __restrict__ as1,
                                                   const float* __restrict__ ad1,
                                                   const int* __restrict__ offsets,
                                                   const int* __restrict__ csr,
                                                   const float* __restrict__ bias,
                                                   float* __restrict__ h1o, int n) {
  int gtid = blockIdx.x * 256 + threadIdx.x;
  int node = gtid >> 6;
  int lane = gtid & 63;
  if (node >= n) return;
  int head = lane >> 3;  // pass B: head of this lane's dims; pass A: head h
  int slot = lane & 7;   // pass A: edge slot
  float ad = ad1[node * 8 + head];
  int beg = offsets[node], end = offsets[node + 1];
  int deg = end - beg;

  // ---- pass A: per-head max, 8 edges in parallel ----
  float m = -INFINITY;
  for (int c0 = 0; c0 < deg; c0 += 64) {
    int cnt = min(64, deg - c0);
    int sreg = (c0 + lane < deg) ? csr[beg + c0 + lane] : 0;
#pragma unroll
    for (int k = 0; k < 8; ++k) {
      int e = slot + k * 8;
      if (e < cnt) {
        int s = __shfl(sreg, e);
        float ev = as1[s * 8 + head] + ad;
        ev = ev > 0.f ? ev : NEG_SLOPE * ev;
        m = fmaxf(m, ev);
      }
    }
  }
  m = fmaxf(m, __shfl_xor(m, 1));
  m = fmaxf(m, __shfl_xor(m, 2));
  m = fmaxf(m, __shfl_xor(m, 4));  // all 8 lanes of each head group share max

  // ---- pass B: weighted sum over bf16 rows ----
  float l = 0.f;
  float ax = 0.f, ay = 0.f, az = 0.f, aw = 0.f;
  for (int c0 = 0; c0 < deg; c0 += 64) {
    int cnt = min(64, deg - c0);
    int sreg = (c0 + lane < deg) ? csr[beg + c0 + lane] : 0;
#pragma unroll 4
    for (int j = 0; j < cnt; ++j) {
      int s = __shfl(sreg, j);
      float ev = as1[s * 8 + head] + ad;
      ev = ev > 0.f ? ev : NEG_SLOPE * ev;
      float pe = __expf(ev - m);
      l += pe;
      ushort4 hv = *(const ushort4*)(h1b + (size_t)s * 256 + lane * 4);
      ax += pe * bf2f(hv.x);
      ay += pe * bf2f(hv.y);
      az += pe * bf2f(hv.z);
      aw += pe * bf2f(hv.w);
    }
  }
  float inv = 1.f / (l + 1e-16f);
  float4 b = *(const float4*)(bias + lane * 4);
  float o0 = ax * inv + b.x, o1 = ay * inv + b.y;
  float o2 = az * inv + b.z, o3 = aw * inv + b.w;
  o0 = o0 > 0.f ? o0 : expm1f(o0);
  o1 = o1 > 0.f ? o1 : expm1f(o1);
  o2 = o2 > 0.f ? o2 : expm1f(o2);
  o3 = o3 > 0.f ? o3 : expm1f(o3);
  *(float4*)(h1o + (size_t)node * 256 + lane * 4) = make_float4(o0, o1, o2, o3);
}

// ---------------- GEMM2: h2b[n,32] = bf16(h1o[n,256] @ W2[256,32]) ----------------

__global__ __launch_bounds__(256) void gemm2_kernel(const float* __restrict__ h1o,
                                                    const float* __restrict__ W2,
                                                    unsigned short* __restrict__ h2b, int n) {
  __shared__ float xst[64][132];
  __shared__ float w2s[64][32];
  int tid = threadIdx.x;
  int row0 = blockIdx.x * 128;
  int r0 = (tid >> 3) * 4, c0 = (tid & 7) * 4;
  float acc[4][4] = {};
  for (int k0 = 0; k0 < 256; k0 += 64) {
#pragma unroll
    for (int i = 0; i < 8; ++i) {
      int flat = tid + i * 256;
      int r = flat >> 4, c4 = flat & 15;
      float4 v = make_float4(0.f, 0.f, 0.f, 0.f);
      int gr = row0 + r;
      if (gr < n) v = *(const float4*)(h1o + (size_t)gr * 256 + k0 + c4 * 4);
      xst[c4 * 4 + 0][r] = v.x;
      xst[c4 * 4 + 1][r] = v.y;
      xst[c4 * 4 + 2][r] = v.z;
      xst[c4 * 4 + 3][r] = v.w;
    }
#pragma unroll
    for (int i = 0; i < 2; ++i) {
      int flat = tid + i * 256;
      int k = flat >> 3, c4 = flat & 7;
      *(float4*)&w2s[k][c4 * 4] = *(const float4*)(W2 + (size_t)(k0 + k) * 32 + c4 * 4);
    }
    __syncthreads();
    for (int k = 0; k < 64; ++k) {
      float4 xv = *(const float4*)&xst[k][r0];
      float4 wv = *(const float4*)&w2s[k][c0];
      float xa[4] = {xv.x, xv.y, xv.z, xv.w};
      float wa[4] = {wv.x, wv.y, wv.z, wv.w};
#pragma unroll
      for (int i2 = 0; i2 < 4; ++i2)
#pragma unroll
        for (int j = 0; j < 4; ++j) acc[i2][j] += xa[i2] * wa[j];
    }
    __syncthreads();
  }
#pragma unroll
  for (int i2 = 0; i2 < 4; ++i2) {
    int gr = row0 + r0 + i2;
    if (gr < n) {
      ushort4 o;
      o.x = f2bf(acc[i2][0]);
      o.y = f2bf(acc[i2][1]);
      o.z = f2bf(acc[i2][2]);
      o.w = f2bf(acc[i2][3]);
      *(ushort4*)(h2b + (size_t)gr * 32 + c0) = o;
    }
  }
}

// ---------------- attention coefficients, layer 2 (1 head) ----------------

__global__ __launch_bounds__(256) void att2_kernel(const unsigned short* __restrict__ h2b,
                                                   const float* __restrict__ att_src,
                                                   const float* __restrict__ att_dst,
                                                   float* __restrict__ as2,
                                                   float* __restrict__ ad2, int n) {
  int node = blockIdx.x * 256 + threadIdx.x;
  if (node >= n) return;
  const ushort4* hp = (const ushort4*)(h2b + (size_t)node * 32);
  const float4* ap = (const float4*)att_src;
  const float4* bp = (const float4*)att_dst;
  float s1 = 0.f, s2 = 0.f;
#pragma unroll
  for (int c = 0; c < 8; ++c) {
    ushort4 u = hp[c];
    float4 a = ap[c], b = bp[c];
    float vx = bf2f(u.x), vy = bf2f(u.y), vz = bf2f(u.z), vw = bf2f(u.w);
    s1 += vx * a.x + vy * a.y + vz * a.z + vw * a.w;
    s2 += vx * b.x + vy * b.y + vz * b.z + vw * b.w;
  }
  as2[node] = s1;
  ad2[node] = s2;
}

// ---------------- layer-2 aggregation: 32 lanes per node ----------------

__global__ __launch_bounds__(256) void agg2_kernel(const unsigned short* __restrict__ h2b,
                                                   const float* __restrict__ as2,
                                                   const float* __restrict__ ad2,
                                                   const int* __restrict__ offsets,
                                                   const int* __restrict__ csr,
                                                   const float* __restrict__ bias,
                                                   float* __restrict__ h2o, int n) {
  int gtid = blockIdx.x * 256 + threadIdx.x;
  int node = gtid >> 5;
  int lane = gtid & 31;
  if (node >= n) return;
  float ad = ad2[node];
  int beg = offsets[node], end = offsets[node + 1];
  int deg = end - beg;

  // pass A: 32 edges in parallel
  float m = -INFINITY;
  for (int e = lane; e < deg; e += 32) {
    int s = csr[beg + e];
    float ev = as2[s] + ad;
    ev = ev > 0.f ? ev : NEG_SLOPE * ev;
    m = fmaxf(m, ev);
  }
  m = fmaxf(m, __shfl_xor(m, 1, 32));
  m = fmaxf(m, __shfl_xor(m, 2, 32));
  m = fmaxf(m, __shfl_xor(m, 4, 32));
  m = fmaxf(m, __shfl_xor(m, 8, 32));
  m = fmaxf(m, __shfl_xor(m, 16, 32));

  // pass B
  float l = 0.f, acc = 0.f;
  for (int c0 = 0; c0 < deg; c0 += 32) {
    int cnt = min(32, deg - c0);
    int sreg = (c0 + lane < deg) ? csr[beg + c0 + lane] : 0;
#pragma unroll 4
    for (int j = 0; j < cnt; ++j) {
      int s = __shfl(sreg, j, 32);
      float ev = as2[s] + ad;
      ev = ev > 0.f ? ev : NEG_SLOPE * ev;
      float pe = __expf(ev - m);
      l += pe;
      acc += pe * bf2f(h2b[(size_t)s * 32 + lane]);
    }
  }
  float o = acc / (l + 1e-16f) + bias[lane];
  h2o[(size_t)node * 32 + lane] = o > 0.f ? o : expm1f(o);
}

// ---------------- final: out[n,16] = h2o[n,32] @ Wout[32,16] + bout ----------------

__global__ __launch_bounds__(256) void final_kernel(const float* __restrict__ h2o,
                                                    const float* __restrict__ Wout,
                                                    const float* __restrict__ bout,
                                                    float* __restrict__ out, int n) {
  int t = blockIdx.x * 256 + threadIdx.x;
  if (t >= n * 16) return;
  int node = t >> 4, f = t & 15;
  const float* hp = h2o + (size_t)node * 32;
  float s = bout[f];
#pragma unroll
  for (int c = 0; c < 32; ++c) s += hp[c] * Wout[c * 16 + f];
  out[t] = s;
}

// ---------------- launch ----------------

extern "C" void kernel_launch(void* const* d_in, const int* in_sizes, int n_in,
                              void* d_out, int out_size, void* d_ws, size_t ws_size,
                              hipStream_t stream) {
  const float* x        = (const float*)d_in[0];
  const int*   ei       = (const int*)d_in[1];
  const float* W1       = (const float*)d_in[2];
  const float* att_src1 = (const float*)d_in[3];
  const float* att_dst1 = (const float*)d_in[4];
  const float* b1       = (const float*)d_in[5];
  const float* W2       = (const float*)d_in[6];
  const float* att_src2 = (const float*)d_in[7];
  const float* att_dst2 = (const float*)d_in[8];
  const float* b2       = (const float*)d_in[9];
  const float* Wout     = (const float*)d_in[10];
  const float* bout     = (const float*)d_in[11];
  float* out = (float*)d_out;

  int n = in_sizes[0] / 128;  // 50000
  int e = in_sizes[1] / 2;    // 800000

  char* w = (char*)d_ws;
  unsigned short* h1b = (unsigned short*)w; w += (size_t)n * 256 * 2;
  float* h1o  = (float*)w; w += (size_t)n * 256 * 4;
  unsigned short* h2b = (unsigned short*)w; w += (size_t)n * 32 * 2;
  float* h2o  = (float*)w; w += (size_t)n * 32 * 4;
  float* as1  = (float*)w; w += (size_t)n * 8 * 4;
  float* ad1  = (float*)w; w += (size_t)n * 8 * 4;
  float* as2  = (float*)w; w += (size_t)n * 4;
  float* ad2  = (float*)w; w += (size_t)n * 4;
  int* counts  = (int*)w; w += (size_t)n * 4;
  int* offsets = (int*)w; w += (size_t)(n + 1) * 4;
  int* cursor  = (int*)w; w += (size_t)n * 4;
  int* csr     = (int*)w; w += (size_t)(e + n) * 4;
  int* bsum    = (int*)w; w += (size_t)256 * 4;

  int nb = (n + SCAN_TILE - 1) / SCAN_TILE;

  // CSR by dst
  hipMemsetAsync(counts, 0, (size_t)n * 4, stream);
  hist_kernel<<<(e + 255) / 256, 256, 0, stream>>>(ei, counts, e);
  scan1_kernel<<<nb, 1024, 0, stream>>>(counts, offsets, bsum, n);
  scan2_kernel<<<1, 64, 0, stream>>>(bsum, nb);
  scan3_kernel<<<(n + 256) / 256, 256, 0, stream>>>(counts, offsets, bsum, n, nb);
  hipMemcpyAsync(cursor, offsets, (size_t)n * 4, hipMemcpyDeviceToDevice, stream);
  fill_kernel<<<(e + n + 255) / 256, 256, 0, stream>>>(ei, cursor, csr, n, e);

  // layer 1
  gemm1_kernel<<<dim3((n + 63) / 64, 4), 256, 0, stream>>>(x, W1, h1b, n);
  att1_kernel<<<(n * 8 + 255) / 256, 256, 0, stream>>>(h1b, att_src1, att_dst1, as1, ad1, n);
  agg1_kernel<<<(n + 3) / 4, 256, 0, stream>>>(h1b, as1, ad1, offsets, csr, b1, h1o, n);

  // layer 2
  gemm2_kernel<<<(n + 127) / 128, 256, 0, stream>>>(h1o, W2, h2b, n);
  att2_kernel<<<(n + 255) / 256, 256, 0, stream>>>(h2b, att_src2, att_dst2, as2, ad2, n);
  agg2_kernel<<<(n * 8 * 32 / 8 + 255) / 256, 256, 0, stream>>>(h2b, as2, ad2, offsets, csr, b2, h2o, n);

  // output projection
  final_kernel<<<(n * 16 + 255) / 256, 256, 0, stream>>>(h2o, Wout, bout, out, n);
}